// Round 1
// baseline (217.140 us; speedup 1.0000x reference)
//
#include <hip/hip_runtime.h>
#include <math.h>

// MegalodonEMA: out[l,b,d] = silu( sum_{m<=l} K[d,m]*x[l-m,b,d] + x[l,b,d]*rw[d] )
// K[d,m] = sum_n c[d,n] * w[d,n]^m  with
//   w = 1 - sigmoid(damping)*sigmoid(decay),  c = sigmoid(damping)*ema*proj/8
// => 64-state linear recurrence per (b,d): h_n[l] = w_n h_n[l-1] + x[l];
//    y[l] = sum_n c_n h_n[l].
// One wave per (b,d); lane = state n. Chunked (C=32) scan with LDS-transposed
// reduction to avoid a per-timestep cross-lane sum.

#define L_SEQ 2048
#define BSZ 8
#define DIM 1024
#define NDIM 64
#define CHUNK 32
#define NCHUNK (L_SEQ / CHUNK) // 64
#define BD (BSZ * DIM)         // 8192
#define PPITCH (CHUNK + 1)     // 33: pad -> bank = (n+j)%32, 2-way (free)

__global__ __launch_bounds__(64) void mega_ema_kernel(
    const float* __restrict__ x,
    const float* __restrict__ damping_factor,
    const float* __restrict__ decay_factor,
    const float* __restrict__ ema_mat,
    const float* __restrict__ proj,
    const float* __restrict__ rw,
    float* __restrict__ out)
{
    __shared__ float xt[CHUNK];
    __shared__ float P[NDIM * PPITCH];

    // XCD-chunked swizzle: batch b -> one XCD, so waves for adjacent d
    // (which share x cache lines; x is (L,B,D)) live on the same L2.
    int bid = blockIdx.x;
    int sid = (bid & 7) * 1024 + (bid >> 3); // 8192 blocks, bijective
    int b = sid / DIM;
    int d = sid % DIM;
    int lane = threadIdx.x; // 0..63 = state n

    // per-(d,n) params (coalesced 256B row reads)
    int pidx = d * NDIM + lane;
    float df = damping_factor[pidx];
    float cf = decay_factor[pidx];
    float em = ema_mat[pidx];
    float pj = proj[pidx];
    float damping = 1.0f / (1.0f + expf(-df));
    float decay   = 1.0f / (1.0f + expf(-cf));
    float w = 1.0f - damping * decay;
    float c = damping * em * pj * 0.125f; // 1/sqrt(64)
    float rwd = rw[d];

    const float* xcol = x + (size_t)b * DIM + d;
    float*       ocol = out + (size_t)b * DIM + d;

    float h = 0.0f;
    int j32  = lane & 31;
    int half = lane >> 5;

    for (int g = 0; g < NCHUNK; ++g) {
        int l0 = g * CHUNK;
        // stage this chunk's x column (stride-BD scatter; L2 absorbs via
        // 16 d-adjacent waves sharing each 64B line)
        if (lane < CHUNK) {
            xt[lane] = xcol[(size_t)(l0 + lane) * BD];
        }
        __syncthreads();

        // phase 1: 32 scan steps; lane n writes c_n*h_n[j] to P[n][j]
        #pragma unroll
        for (int j = 0; j < CHUNK; ++j) {
            float xv = xt[j];          // same-address LDS broadcast
            h = fmaf(w, h, xv);
            P[lane * PPITCH + j] = c * h;
        }
        __syncthreads();

        // phase 2: lane (half,j32) sums 32 states; halves combined by shfl
        float psum = 0.0f;
        #pragma unroll
        for (int i = 0; i < 32; ++i) {
            psum += P[(half * 32 + i) * PPITCH + j32];
        }
        float y = psum + __shfl_xor(psum, 32);

        if (lane < CHUNK) {
            float xv = xt[lane];
            float v = y + xv * rwd;          // + residual
            float s = v / (1.0f + __expf(-v)); // silu
            ocol[(size_t)(l0 + lane) * BD] = s;
        }
        __syncthreads(); // protect xt/P before next chunk
    }
}

extern "C" void kernel_launch(void* const* d_in, const int* in_sizes, int n_in,
                              void* d_out, int out_size, void* d_ws, size_t ws_size,
                              hipStream_t stream) {
    const float* x   = (const float*)d_in[0];
    const float* df  = (const float*)d_in[1];
    const float* cf  = (const float*)d_in[2];
    const float* em  = (const float*)d_in[3];
    const float* pj  = (const float*)d_in[4];
    const float* rw  = (const float*)d_in[5];
    float* out = (float*)d_out;

    dim3 grid(BSZ * DIM); // 8192 waves, one per (b,d)
    dim3 block(64);
    mega_ema_kernel<<<grid, block, 0, stream>>>(x, df, cf, em, pj, rw, out);
}